// Round 14
// baseline (374.338 us; speedup 1.0000x reference)
//
#include <hip/hip_runtime.h>

#define NS   50000
#define LSEQ 32
#define IND  64
#define HIDN 64
#define OUTD 128
#define NR   11

using bf16x8  = __attribute__((ext_vector_type(8))) short;
using f32x16  = __attribute__((ext_vector_type(16))) float;

union U8 { bf16x8 v; unsigned u[4]; uint2 d[2]; };

__device__ __forceinline__ unsigned cvt_pk_bf16(float a, float b) {
  unsigned r;
  asm volatile("v_cvt_pk_bf16_f32 %0, %1, %2" : "=v"(r) : "v"(a), "v"(b));
  return r;  // r[15:0] = bf16(a), r[31:16] = bf16(b)
}
__device__ __forceinline__ float fsig(float x) {
  return __builtin_amdgcn_rcpf(1.f + __expf(-x));
}
__device__ __forceinline__ float ftanh_(float x) {
  return 1.f - 2.f * __builtin_amdgcn_rcpf(__expf(2.f * x) + 1.f);
}

// ---------------- feature table -> bf16 (halves gather traffic) ------------
__global__ __launch_bounds__(256) void fprep_kernel(
    const float* __restrict__ f, unsigned* __restrict__ fb) {
  int i = blockIdx.x * 256 + threadIdx.x;      // uint index (2 floats)
  if (i < NS * IND / 2) {
    float2 v = ((const float2*)f)[i];
    fb[i] = cvt_pk_bf16(v.x, v.y);
  }
}

// ---------------- length sort (descending), LDS-binned ---------------------
__global__ void zero_cnt_kernel(int* cnt) {
  if (threadIdx.x < 64) cnt[threadIdx.x] = 0;  // cnt[32] + cur[32]
}
__global__ __launch_bounds__(256) void hist_kernel(
    const int* __restrict__ lens, int* __restrict__ cnt) {
  __shared__ int lc[32];
  int t = threadIdx.x;
  if (t < 32) lc[t] = 0;
  __syncthreads();
  int s = blockIdx.x * 256 + t;
  if (s < NS) atomicAdd(&lc[32 - lens[s]], 1);
  __syncthreads();
  if (t < 32 && lc[t]) atomicAdd(&cnt[t], lc[t]);
}
__global__ void prefix_kernel(const int* __restrict__ cnt, int* __restrict__ cur) {
  if (threadIdx.x == 0) {
    int sum = 0;
    for (int b = 0; b < 32; ++b) { cur[b] = sum; sum += cnt[b]; }
  }
}
__global__ __launch_bounds__(256) void scatter_kernel(
    const int* __restrict__ lens, int* __restrict__ cur, int* __restrict__ ord) {
  __shared__ int lc[32], lb[32];
  int t = threadIdx.x;
  if (t < 32) lc[t] = 0;
  __syncthreads();
  int s = blockIdx.x * 256 + t;
  int rank = 0, bin = 0;
  if (s < NS) {
    bin = 32 - lens[s];
    rank = atomicAdd(&lc[bin], 1);      // LDS atomic (fast)
  }
  __syncthreads();
  if (t < 32 && lc[t]) lb[t] = atomicAdd(&cur[t], lc[t]);  // 32/block global
  __syncthreads();
  if (s < NS) ord[lb[bin] + rank] = s;
}

// ---------------------------------------------------------------------------
// Prep: Wr[11][64][128] f32 -> wt2: per-lane-major A fragments for the fused
// projection. frag_idx = ((r*4+nt)*4+kc)*2+pl; u32 offset = frag_idx*256 +
// lane*4; each 16B = W^T(pl)[row=nt*32+(lane&31)][k0..k0+7], k0=kc*16+(lane>>5)*8.
// ---------------------------------------------------------------------------
__global__ __launch_bounds__(256) void wprep_kernel(
    const float* __restrict__ Wr, unsigned* __restrict__ wt2)
{
  __shared__ float wl[64 * 128];
  const int r = blockIdx.x;
  for (int i = threadIdx.x; i < 64 * 128; i += 256)
    wl[i] = Wr[r * 64 * 128 + i];
  __syncthreads();
  for (int idx = threadIdx.x; idx < 2048; idx += 256) {
    int lane = idx & 63;
    int pl   = (idx >> 6) & 1;
    int kc   = (idx >> 7) & 3;
    int nt   = (idx >> 9) & 3;
    int row  = nt * 32 + (lane & 31);          // out index o
    int k0   = kc * 16 + (lane >> 5) * 8;      // hidden-unit k
    unsigned o4[4];
#pragma unroll
    for (int jp = 0; jp < 4; ++jp) {
      float a = wl[(k0 + jp * 2) * 128 + row];      // W[k][o]
      float b = wl[(k0 + jp * 2 + 1) * 128 + row];
      unsigned h = cvt_pk_bf16(a, b);
      if (pl) {
        float la = a - __uint_as_float(h << 16);
        float lb = b - __uint_as_float(h & 0xffff0000u);
        h = cvt_pk_bf16(la, lb);
      }
      o4[jp] = h;
    }
    size_t dst = (size_t)(((r * 4 + nt) * 4 + kc) * 2 + pl) * 256 + lane * 4;
    *(uint4*)(wt2 + dst) = *(uint4*)o4;
  }
}

// ---------------------------------------------------------------------------
// K1: FULLY FUSED gather + bf16-MFMA LSTM + relation pooling + projection +
// atomic scatter. 512 thr / 8 waves; 64 samples/block as TWO SEQUENTIAL
// 32-sample passes sharing one Af load (block count and Af traffic halve).
// EPILOGUE IS R12'S VERBATIM (mw waves 0-3, pb[2], 4-term split-bf16, direct
// atomic) -- R13's wave-split epilogue reverted (accuracy bisection).
// ---------------------------------------------------------------------------
__global__ __launch_bounds__(512, 4) void lstm_mfma_kernel(
    const unsigned* __restrict__ fb, const int* __restrict__ nbr,
    const int* __restrict__ lens, const int* __restrict__ rels,
    const float* __restrict__ adjw, const float* __restrict__ Wih,
    const float* __restrict__ Whh, const int* __restrict__ ord,
    const int* __restrict__ nodes, const unsigned* __restrict__ wt2,
    float* __restrict__ out, int s0, int cnt)
{
  // arena: [0,8192) xq = 4 slots x [32 s][128B x]; [8192,12288) hb = 2 bufs.
  // Epilogue aliases arena[0,8704) as pb (2 x [32 s][136 shorts]).
  __shared__ __align__(16) short arena[12288];     // 24KB
  __shared__ float sh_w[32][33];
  __shared__ int   sh_meta[32][33];    // rel<<16 | nbr (nbr < 2^16)
  __shared__ int   sh_len[32];
  __shared__ int   sh_nodes[32];

  const int tid   = threadIdx.x;
  const int lane  = tid & 63;
  const int w     = tid >> 6;
  const int sbase = blockIdx.x * 64;

  // stationary A fragments (gate-permuted weight rows, bf16) -- ONCE per block
  bf16x8 Af[8];
  {
    const int rr = lane & 31, kh = lane >> 5;
    const int g = rr & 3, q = rr >> 2;
    const int u = w * 8 + 4 * (q & 1) + (q >> 1);
    const int row = g * 64 + u;
#pragma unroll
    for (int kc = 0; kc < 8; ++kc) {
      int k0 = kc * 16 + kh * 8;
      const float* src = (k0 < 64) ? (Wih + row * 64 + k0)
                                   : (Whh + row * 64 + (k0 - 64));
      float4 f0 = *(const float4*)(src);
      float4 f1 = *(const float4*)(src + 4);
      U8 a;
      a.u[0] = cvt_pk_bf16(f0.x, f0.y); a.u[1] = cvt_pk_bf16(f0.z, f0.w);
      a.u[2] = cvt_pk_bf16(f1.x, f1.y); a.u[3] = cvt_pk_bf16(f1.z, f1.w);
      Af[kc] = a.v;
    }
  }

  const int s   = lane & 31;           // gate-phase / B-col sample
  const int hi  = lane >> 5;
  const int sx3 = (s & 7) << 4;        // 128B-row granule XOR
  const int u0  = w * 8 + 4 * hi;      // 4 consecutive units
  int rofs[4];
#pragma unroll
  for (int kc = 0; kc < 4; ++kc)
    rofs[kc] = s * 64 + (((kc * 32 + hi * 16) ^ sx3) >> 1);
  const int hofs = s * 64 + (((u0 * 2) ^ sx3) >> 1);

  // stage x for timestep ts, samples [sb, sb+8): 1 wave-load, 1KB linear dest.
  auto stage_x = [&](int ts, int sb) {
    int s_l  = sb + (lane >> 3);
    int gl   = lane & 7;
    int nid  = sh_meta[s_l][ts] & 0xffff;
    int perm = gl ^ (s_l & 7);
    __builtin_amdgcn_global_load_lds(
        (const __attribute__((address_space(1))) unsigned*)
            (fb + (size_t)nid * 32 + perm * 4),
        (__attribute__((address_space(3))) unsigned*)
            (&arena[(ts & 3) * 2048 + sb * 64]),
        16, 0, 0);
  };

#pragma unroll 1
  for (int pass = 0; pass < 2; ++pass) {
    const int pbase = sbase + pass * 32;

    // ---- per-pass prologue: metadata + h=0 ----
    for (int i = tid; i < 32 * 32; i += 512) {
      int ss = i >> 5, l = i & 31;
      int gp = pbase + ss;
      bool ok = gp < cnt;
      int gs = ok ? ord[s0 + gp] : 0;
      size_t off = (size_t)gs * LSEQ + l;
      sh_w[ss][l]    = ok ? adjw[off] : 0.f;
      sh_meta[ss][l] = ok ? ((rels[off] << 16) | nbr[off]) : 0;
    }
    if (tid < 32) {
      int gp = pbase + tid;
      bool ok = gp < cnt;
      int gs = ok ? ord[s0 + gp] : 0;
      sh_len[tid]   = ok ? lens[gs] : 0;
      sh_nodes[tid] = ok ? nodes[gs] : 0;
    }
    for (int i = tid; i < 2 * 32 * 64; i += 512) arena[8192 + i] = 0;  // h(0)=0

    float c4[4] = {0.f, 0.f, 0.f, 0.f};
    float pooled[4][NR] = {};

    __syncthreads();                   // meta + hb ready
    const int len_s = sh_len[s];
    const int tmax  = sh_len[0];       // pass max (descending sort)

    {  // stage chunk {0,1}; wave w -> ts = w>>2, sb = (w&3)*8
      int ts = w >> 2;
      if (ts < tmax) stage_x(ts, (w & 3) * 8);
    }
    __syncthreads();

#pragma unroll 1
    for (int t = 0; t < tmax; ++t) {
      if ((t & 1) == 1 && t + 1 < tmax) {
        int ts = t + 1 + (w >> 2);
        if (ts < tmax) stage_x(ts, (w & 3) * 8);
      }

      const short* xp = &arena[(t & 3) * 2048];
      const short* hp = &arena[8192 + (t & 1) * 2048];
      f32x16 acc = {};
#pragma unroll
      for (int kc = 0; kc < 4; ++kc) {
        bf16x8 b = *(const bf16x8*)(&xp[rofs[kc]]);
        acc = __builtin_amdgcn_mfma_f32_32x32x16_bf16(Af[kc], b, acc, 0, 0, 0);
      }
#pragma unroll
      for (int kc = 0; kc < 4; ++kc) {
        bf16x8 b = *(const bf16x8*)(&hp[rofs[kc]]);
        acc = __builtin_amdgcn_mfma_f32_32x32x16_bf16(Af[kc + 4], b, acc, 0, 0, 0);
      }

      int pk = sh_meta[s][t];
      float wv = (t < len_s) ? sh_w[s][t] : 0.f;
      int rl = pk >> 16;
      float h4[4];
#pragma unroll
      for (int p = 0; p < 4; ++p) {
        float gi = fsig(acc[4 * p + 0]);
        float gf = fsig(acc[4 * p + 1]);
        float gg = ftanh_(acc[4 * p + 2]);
        float go = fsig(acc[4 * p + 3]);
        float cc = gf * c4[p] + gi * gg;
        c4[p] = cc;
        h4[p] = go * ftanh_(cc);
      }
#pragma unroll
      for (int r = 0; r < NR; ++r) {
        float mr = (rl == r) ? wv : 0.f;
        pooled[0][r] += mr * h4[0]; pooled[1][r] += mr * h4[1];
        pooled[2][r] += mr * h4[2]; pooled[3][r] += mr * h4[3];
      }

      *(uint2*)&arena[8192 + ((t & 1) ^ 1) * 2048 + hofs] =
          make_uint2(cvt_pk_bf16(h4[0], h4[1]), cvt_pk_bf16(h4[2], h4[3]));
      __syncthreads();
    }

    // ---- fused projection epilogue (R12 VERBATIM): proj = sum_r P_r @ W_r --
    short* pb = arena;                 // [2][32][136] shorts
    f32x16 pacc = {};
    const bool mw = (w < 4);           // MFMA waves; wave w owns out rows w*32..+31
#pragma unroll
    for (int rr = 0; rr < 12; rr += 2) {
#pragma unroll
      for (int p = 0; p < 2; ++p) {
        int r = rr + p;
        if (r < NR) {
          float p0 = pooled[0][r], p1 = pooled[1][r];
          float p2 = pooled[2][r], p3 = pooled[3][r];
          unsigned h0 = cvt_pk_bf16(p0, p1), h1 = cvt_pk_bf16(p2, p3);
          float l0 = p0 - __uint_as_float(h0 << 16);
          float l1 = p1 - __uint_as_float(h0 & 0xffff0000u);
          float l2 = p2 - __uint_as_float(h1 << 16);
          float l3 = p3 - __uint_as_float(h1 & 0xffff0000u);
          unsigned g0 = cvt_pk_bf16(l0, l1), g1 = cvt_pk_bf16(l2, l3);
          *(uint2*)&pb[p * 4352 + s * 136 + u0]      = make_uint2(h0, h1);
          *(uint2*)&pb[p * 4352 + s * 136 + 64 + u0] = make_uint2(g0, g1);
        }
      }
      __syncthreads();
      if (mw) {
#pragma unroll
        for (int p = 0; p < 2; ++p) {
          int r = rr + p;
          if (r < NR) {
#pragma unroll
            for (int kc = 0; kc < 4; ++kc) {
              int fi = ((r * 4 + w) * 4 + kc) * 2;
              U8 ah, al;
              *(uint4*)ah.u = *(const uint4*)(wt2 + (size_t)fi * 256 + lane * 4);
              *(uint4*)al.u = *(const uint4*)(wt2 + (size_t)(fi + 1) * 256 + lane * 4);
              bf16x8 bh = *(const bf16x8*)(&pb[p * 4352 + s * 136 + kc * 16 + hi * 8]);
              bf16x8 bl = *(const bf16x8*)(&pb[p * 4352 + s * 136 + 64 + kc * 16 + hi * 8]);
              pacc = __builtin_amdgcn_mfma_f32_32x32x16_bf16(ah.v, bh, pacc, 0, 0, 0);
              pacc = __builtin_amdgcn_mfma_f32_32x32x16_bf16(ah.v, bl, pacc, 0, 0, 0);
              pacc = __builtin_amdgcn_mfma_f32_32x32x16_bf16(al.v, bh, pacc, 0, 0, 0);
              pacc = __builtin_amdgcn_mfma_f32_32x32x16_bf16(al.v, bl, pacc, 0, 0, 0);
            }
          }
        }
      }
      __syncthreads();
    }

    if (mw && (pbase + s) < cnt) {
      int nd = sh_nodes[s];
      float* dst = out + (size_t)nd * OUTD + w * 32;
#pragma unroll
      for (int j = 0; j < 16; ++j) {
        int m = (j & 3) + 8 * (j >> 2) + 4 * hi;
        atomicAdd(dst + m, pacc[j]);
      }
    }
    __syncthreads();                   // sh_*/arena reuse safe for next pass
  }
}

__global__ void relu_kernel(float4* __restrict__ out, int n4) {
  int i = blockIdx.x * 256 + threadIdx.x;
  if (i < n4) {
    float4 v = out[i];
    v.x = fmaxf(v.x, 0.f); v.y = fmaxf(v.y, 0.f);
    v.z = fmaxf(v.z, 0.f); v.w = fmaxf(v.w, 0.f);
    out[i] = v;
  }
}

extern "C" void kernel_launch(void* const* d_in, const int* in_sizes, int n_in,
                              void* d_out, int out_size, void* d_ws, size_t ws_size,
                              hipStream_t stream) {
  const int*   nbr   = (const int*)d_in[0];
  const int*   lens  = (const int*)d_in[1];
  const int*   rels  = (const int*)d_in[2];
  const int*   nodes = (const int*)d_in[3];
  const float* adjw  = (const float*)d_in[4];
  const float* feat  = (const float*)d_in[5];
  const float* Wih   = (const float*)d_in[6];
  const float* Whh   = (const float*)d_in[7];
  const float* Wr    = (const float*)d_in[8];
  float* out = (float*)d_out;

  hipMemsetAsync(d_out, 0, (size_t)NS * OUTD * sizeof(float), stream);

  // ws layout: wt2 [0,360448) | fb bf16 feat [360448, 6760448) |
  //            ord [6760448, 6960448) | cnt/cur [6960448, +256)
  unsigned* wt2 = (unsigned*)d_ws;
  unsigned* fb  = (unsigned*)((char*)d_ws + 360448);
  int*      ord = (int*)((char*)d_ws + 6760448);
  int*      cnt = (int*)((char*)d_ws + 6960448);
  int*      cur = cnt + 32;

  wprep_kernel<<<NR, 256, 0, stream>>>(Wr, wt2);
  fprep_kernel<<<(NS * IND / 2 + 255) / 256, 256, 0, stream>>>(feat, fb);
  zero_cnt_kernel<<<1, 64, 0, stream>>>(cnt);
  hist_kernel<<<(NS + 255) / 256, 256, 0, stream>>>(lens, cnt);
  prefix_kernel<<<1, 64, 0, stream>>>(cnt, cur);
  scatter_kernel<<<(NS + 255) / 256, 256, 0, stream>>>(lens, cur, ord);

  lstm_mfma_kernel<<<(NS + 63) / 64, 512, 0, stream>>>(
      fb, nbr, lens, rels, adjw, Wih, Whh, ord, nodes, wt2, out, 0, NS);

  relu_kernel<<<(NS * OUTD / 4 + 255) / 256, 256, 0, stream>>>(
      (float4*)out, NS * OUTD / 4);
}

// Round 15
// 307.687 us; speedup vs baseline: 1.2166x; 1.2166x over previous
//
#include <hip/hip_runtime.h>

#define NS   50000
#define LSEQ 32
#define IND  64
#define HIDN 64
#define OUTD 128
#define NR   11

using bf16x8  = __attribute__((ext_vector_type(8))) short;
using f32x16  = __attribute__((ext_vector_type(16))) float;

union U8 { bf16x8 v; unsigned u[4]; uint2 d[2]; };

__device__ __forceinline__ unsigned cvt_pk_bf16(float a, float b) {
  unsigned r;
  asm volatile("v_cvt_pk_bf16_f32 %0, %1, %2" : "=v"(r) : "v"(a), "v"(b));
  return r;  // r[15:0] = bf16(a), r[31:16] = bf16(b)
}
__device__ __forceinline__ float fsig(float x) {
  return __builtin_amdgcn_rcpf(1.f + __expf(-x));
}
__device__ __forceinline__ float ftanh_(float x) {
  return 1.f - 2.f * __builtin_amdgcn_rcpf(__expf(2.f * x) + 1.f);
}

// ---------------- feature table -> bf16 (halves gather traffic) ------------
__global__ __launch_bounds__(256) void fprep_kernel(
    const float* __restrict__ f, unsigned* __restrict__ fb) {
  int i = blockIdx.x * 256 + threadIdx.x;      // uint index (2 floats)
  if (i < NS * IND / 2) {
    float2 v = ((const float2*)f)[i];
    fb[i] = cvt_pk_bf16(v.x, v.y);
  }
}

// ---------------- length sort (descending), LDS-binned ---------------------
__global__ void zero_cnt_kernel(int* cnt) {
  if (threadIdx.x < 64) cnt[threadIdx.x] = 0;  // cnt[32] + cur[32]
}
__global__ __launch_bounds__(256) void hist_kernel(
    const int* __restrict__ lens, int* __restrict__ cnt) {
  __shared__ int lc[32];
  int t = threadIdx.x;
  if (t < 32) lc[t] = 0;
  __syncthreads();
  int s = blockIdx.x * 256 + t;
  if (s < NS) atomicAdd(&lc[32 - lens[s]], 1);
  __syncthreads();
  if (t < 32 && lc[t]) atomicAdd(&cnt[t], lc[t]);
}
__global__ void prefix_kernel(const int* __restrict__ cnt, int* __restrict__ cur) {
  if (threadIdx.x == 0) {
    int sum = 0;
    for (int b = 0; b < 32; ++b) { cur[b] = sum; sum += cnt[b]; }
  }
}
__global__ __launch_bounds__(256) void scatter_kernel(
    const int* __restrict__ lens, int* __restrict__ cur, int* __restrict__ ord) {
  __shared__ int lc[32], lb[32];
  int t = threadIdx.x;
  if (t < 32) lc[t] = 0;
  __syncthreads();
  int s = blockIdx.x * 256 + t;
  int rank = 0, bin = 0;
  if (s < NS) {
    bin = 32 - lens[s];
    rank = atomicAdd(&lc[bin], 1);      // LDS atomic (fast)
  }
  __syncthreads();
  if (t < 32 && lc[t]) lb[t] = atomicAdd(&cur[t], lc[t]);  // 32/block global
  __syncthreads();
  if (s < NS) ord[lb[bin] + rank] = s;
}

// ---------------------------------------------------------------------------
// Prep: Wr[11][64][128] f32 -> wt2: per-lane-major A fragments for the fused
// projection. frag_idx = ((r*4+nt)*4+kc)*2+pl; u32 offset = frag_idx*256 +
// lane*4; each 16B = W^T(pl)[row=nt*32+(lane&31)][k0..k0+7], k0=kc*16+(lane>>5)*8.
// ---------------------------------------------------------------------------
__global__ __launch_bounds__(256) void wprep_kernel(
    const float* __restrict__ Wr, unsigned* __restrict__ wt2)
{
  __shared__ float wl[64 * 128];
  const int r = blockIdx.x;
  for (int i = threadIdx.x; i < 64 * 128; i += 256)
    wl[i] = Wr[r * 64 * 128 + i];
  __syncthreads();
  for (int idx = threadIdx.x; idx < 2048; idx += 256) {
    int lane = idx & 63;
    int pl   = (idx >> 6) & 1;
    int kc   = (idx >> 7) & 3;
    int nt   = (idx >> 9) & 3;
    int row  = nt * 32 + (lane & 31);          // out index o
    int k0   = kc * 16 + (lane >> 5) * 8;      // hidden-unit k
    unsigned o4[4];
#pragma unroll
    for (int jp = 0; jp < 4; ++jp) {
      float a = wl[(k0 + jp * 2) * 128 + row];      // W[k][o]
      float b = wl[(k0 + jp * 2 + 1) * 128 + row];
      unsigned h = cvt_pk_bf16(a, b);
      if (pl) {
        float la = a - __uint_as_float(h << 16);
        float lb = b - __uint_as_float(h & 0xffff0000u);
        h = cvt_pk_bf16(la, lb);
      }
      o4[jp] = h;
    }
    size_t dst = (size_t)(((r * 4 + nt) * 4 + kc) * 2 + pl) * 256 + lane * 4;
    *(uint4*)(wt2 + dst) = *(uint4*)o4;
  }
}

// ---------------------------------------------------------------------------
// K1: FULLY FUSED gather + bf16-MFMA LSTM + relation pooling + projection +
// atomic scatter. 512 thr / 8 waves / 32 samples (R12 block structure; the
// R14 two-pass Af-hoist reverted -- it spilled Af to scratch, +96MB FETCH).
// R15 change (isolated): epilogue batched 6+5 relations per phase -> 4
// barriers instead of 12. Per-relation write/MFMA code identical to R12;
// only loop grouping + pb slot index differ. pb = 6 slots (52KB, arena
// enlarged); LDS ~61KB -> 2 blocks/CU cap (>= measured ~1.4 residency).
// ---------------------------------------------------------------------------
__global__ __launch_bounds__(512, 4) void lstm_mfma_kernel(
    const unsigned* __restrict__ fb, const int* __restrict__ nbr,
    const int* __restrict__ lens, const int* __restrict__ rels,
    const float* __restrict__ adjw, const float* __restrict__ Wih,
    const float* __restrict__ Whh, const int* __restrict__ ord,
    const int* __restrict__ nodes, const unsigned* __restrict__ wt2,
    float* __restrict__ out, int s0, int cnt)
{
  // arena main-loop layout: [0,8192) xq = 4 slots x [32 s][128B x];
  // [8192,12288) hb = 2 bufs. Epilogue aliases [0,26112) as pb[6][32][136].
  __shared__ __align__(16) short arena[26112];     // 52224 B
  __shared__ float sh_w[32][33];
  __shared__ int   sh_meta[32][33];    // rel<<16 | nbr (nbr < 2^16)
  __shared__ int   sh_len[32];
  __shared__ int   sh_nodes[32];

  const int tid   = threadIdx.x;
  const int lane  = tid & 63;
  const int w     = tid >> 6;
  const int sbase = blockIdx.x * 32;

  for (int i = tid; i < 32 * 32; i += 512) {
    int ss = i >> 5, l = i & 31;
    int gp = sbase + ss;
    bool ok = gp < cnt;
    int gs = ok ? ord[s0 + gp] : 0;
    size_t off = (size_t)gs * LSEQ + l;
    sh_w[ss][l]    = ok ? adjw[off] : 0.f;
    sh_meta[ss][l] = ok ? ((rels[off] << 16) | nbr[off]) : 0;
  }
  if (tid < 32) {
    int gp = sbase + tid;
    bool ok = gp < cnt;
    int gs = ok ? ord[s0 + gp] : 0;
    sh_len[tid]   = ok ? lens[gs] : 0;
    sh_nodes[tid] = ok ? nodes[gs] : 0;
  }
  for (int i = tid; i < 2 * 32 * 64; i += 512) arena[8192 + i] = 0;  // h(0)=0

  // stationary A fragments (gate-permuted weight rows, bf16)
  bf16x8 Af[8];
  {
    const int rr = lane & 31, kh = lane >> 5;
    const int g = rr & 3, q = rr >> 2;
    const int u = w * 8 + 4 * (q & 1) + (q >> 1);
    const int row = g * 64 + u;
#pragma unroll
    for (int kc = 0; kc < 8; ++kc) {
      int k0 = kc * 16 + kh * 8;
      const float* src = (k0 < 64) ? (Wih + row * 64 + k0)
                                   : (Whh + row * 64 + (k0 - 64));
      float4 f0 = *(const float4*)(src);
      float4 f1 = *(const float4*)(src + 4);
      U8 a;
      a.u[0] = cvt_pk_bf16(f0.x, f0.y); a.u[1] = cvt_pk_bf16(f0.z, f0.w);
      a.u[2] = cvt_pk_bf16(f1.x, f1.y); a.u[3] = cvt_pk_bf16(f1.z, f1.w);
      Af[kc] = a.v;
    }
  }

  const int s   = lane & 31;           // gate-phase / B-col sample
  const int hi  = lane >> 5;
  const int sx3 = (s & 7) << 4;        // 128B-row granule XOR
  const int u0  = w * 8 + 4 * hi;      // 4 consecutive units
  int rofs[4];
#pragma unroll
  for (int kc = 0; kc < 4; ++kc)
    rofs[kc] = s * 64 + (((kc * 32 + hi * 16) ^ sx3) >> 1);
  const int hofs = s * 64 + (((u0 * 2) ^ sx3) >> 1);

  // stage x for timestep ts, samples [sb, sb+8): 1 wave-load, 1KB linear dest.
  auto stage_x = [&](int ts, int sb) {
    int s_l  = sb + (lane >> 3);
    int gl   = lane & 7;
    int nid  = sh_meta[s_l][ts] & 0xffff;
    int perm = gl ^ (s_l & 7);
    __builtin_amdgcn_global_load_lds(
        (const __attribute__((address_space(1))) unsigned*)
            (fb + (size_t)nid * 32 + perm * 4),
        (__attribute__((address_space(3))) unsigned*)
            (&arena[(ts & 3) * 2048 + sb * 64]),
        16, 0, 0);
  };

  float c4[4] = {0.f, 0.f, 0.f, 0.f};
  float pooled[4][NR] = {};

  __syncthreads();                     // meta + hb ready (needed by stage_x)
  const int len_s = sh_len[s];
  const int tmax  = sh_len[0];         // block max (descending sort)

  {  // prologue: stage chunk {0,1}; wave w -> ts = w>>2, sb = (w&3)*8
    int ts = w >> 2;
    if (ts < tmax) stage_x(ts, (w & 3) * 8);
  }
  __syncthreads();                     // drain (own) + cross-wave visibility

#pragma unroll 1
  for (int t = 0; t < tmax; ++t) {
    // issue next 2-step chunk at odd t (used from t+1): slots (t+1)&3 and
    // (t+2)&3 are both retired; drain hides in this phase.
    if ((t & 1) == 1 && t + 1 < tmax) {
      int ts = t + 1 + (w >> 2);
      if (ts < tmax) stage_x(ts, (w & 3) * 8);
    }

    const short* xp = &arena[(t & 3) * 2048];
    const short* hp = &arena[8192 + (t & 1) * 2048];
    f32x16 acc = {};
#pragma unroll
    for (int kc = 0; kc < 4; ++kc) {
      bf16x8 b = *(const bf16x8*)(&xp[rofs[kc]]);
      acc = __builtin_amdgcn_mfma_f32_32x32x16_bf16(Af[kc], b, acc, 0, 0, 0);
    }
#pragma unroll
    for (int kc = 0; kc < 4; ++kc) {
      bf16x8 b = *(const bf16x8*)(&hp[rofs[kc]]);
      acc = __builtin_amdgcn_mfma_f32_32x32x16_bf16(Af[kc + 4], b, acc, 0, 0, 0);
    }

    int pk = sh_meta[s][t];
    float wv = (t < len_s) ? sh_w[s][t] : 0.f;
    int rl = pk >> 16;
    float h4[4];
#pragma unroll
    for (int p = 0; p < 4; ++p) {
      float gi = fsig(acc[4 * p + 0]);
      float gf = fsig(acc[4 * p + 1]);
      float gg = ftanh_(acc[4 * p + 2]);
      float go = fsig(acc[4 * p + 3]);
      float cc = gf * c4[p] + gi * gg;
      c4[p] = cc;
      h4[p] = go * ftanh_(cc);
    }
#pragma unroll
    for (int r = 0; r < NR; ++r) {
      float mr = (rl == r) ? wv : 0.f;
      pooled[0][r] += mr * h4[0]; pooled[1][r] += mr * h4[1];
      pooled[2][r] += mr * h4[2]; pooled[3][r] += mr * h4[3];
    }

    *(uint2*)&arena[8192 + ((t & 1) ^ 1) * 2048 + hofs] =
        make_uint2(cvt_pk_bf16(h4[0], h4[1]), cvt_pk_bf16(h4[2], h4[3]));
    __syncthreads();                   // h(t+1) + (every 2nd) staged x ready
  }

  // ---- fused projection epilogue: proj = sum_r pooled_r @ W_r ----
  // Batched 6+5: pb slot j holds relation rbase+j (write and read agree).
  // Per-relation write/MFMA bodies identical to R12's verified epilogue.
  short* pb = arena;                   // [6][32][136] shorts
  f32x16 pacc = {};
  const bool mw = (w < 4);             // MFMA waves; wave w owns out rows w*32..+31
#pragma unroll
  for (int b = 0; b < 2; ++b) {
    const int rbase = b * 6;
#pragma unroll
    for (int j = 0; j < 6; ++j) {
      int r = rbase + j;
      if (r < NR) {
        float p0 = pooled[0][r], p1 = pooled[1][r];
        float p2 = pooled[2][r], p3 = pooled[3][r];
        unsigned h0 = cvt_pk_bf16(p0, p1), h1 = cvt_pk_bf16(p2, p3);
        float l0 = p0 - __uint_as_float(h0 << 16);
        float l1 = p1 - __uint_as_float(h0 & 0xffff0000u);
        float l2 = p2 - __uint_as_float(h1 << 16);
        float l3 = p3 - __uint_as_float(h1 & 0xffff0000u);
        unsigned g0 = cvt_pk_bf16(l0, l1), g1 = cvt_pk_bf16(l2, l3);
        *(uint2*)&pb[j * 4352 + s * 136 + u0]      = make_uint2(h0, h1);
        *(uint2*)&pb[j * 4352 + s * 136 + 64 + u0] = make_uint2(g0, g1);
      }
    }
    __syncthreads();                   // all 6 slots ready
    if (mw) {
#pragma unroll
      for (int j = 0; j < 6; ++j) {
        int r = rbase + j;
        if (r < NR) {
#pragma unroll
          for (int kc = 0; kc < 4; ++kc) {
            int fi = ((r * 4 + w) * 4 + kc) * 2;
            U8 ah, al;
            *(uint4*)ah.u = *(const uint4*)(wt2 + (size_t)fi * 256 + lane * 4);
            *(uint4*)al.u = *(const uint4*)(wt2 + (size_t)(fi + 1) * 256 + lane * 4);
            bf16x8 bh = *(const bf16x8*)(&pb[j * 4352 + s * 136 + kc * 16 + hi * 8]);
            bf16x8 bl = *(const bf16x8*)(&pb[j * 4352 + s * 136 + 64 + kc * 16 + hi * 8]);
            pacc = __builtin_amdgcn_mfma_f32_32x32x16_bf16(ah.v, bh, pacc, 0, 0, 0);
            pacc = __builtin_amdgcn_mfma_f32_32x32x16_bf16(ah.v, bl, pacc, 0, 0, 0);
            pacc = __builtin_amdgcn_mfma_f32_32x32x16_bf16(al.v, bh, pacc, 0, 0, 0);
            pacc = __builtin_amdgcn_mfma_f32_32x32x16_bf16(al.v, bl, pacc, 0, 0, 0);
          }
        }
      }
    }
    __syncthreads();                   // pb reusable for next batch
  }

  if (mw && (sbase + s) < cnt) {
    int nd = sh_nodes[s];
    float* dst = out + (size_t)nd * OUTD + w * 32;
#pragma unroll
    for (int j = 0; j < 16; ++j) {
      int m = (j & 3) + 8 * (j >> 2) + 4 * hi;
      atomicAdd(dst + m, pacc[j]);
    }
  }
}

__global__ void relu_kernel(float4* __restrict__ out, int n4) {
  int i = blockIdx.x * 256 + threadIdx.x;
  if (i < n4) {
    float4 v = out[i];
    v.x = fmaxf(v.x, 0.f); v.y = fmaxf(v.y, 0.f);
    v.z = fmaxf(v.z, 0.f); v.w = fmaxf(v.w, 0.f);
    out[i] = v;
  }
}

extern "C" void kernel_launch(void* const* d_in, const int* in_sizes, int n_in,
                              void* d_out, int out_size, void* d_ws, size_t ws_size,
                              hipStream_t stream) {
  const int*   nbr   = (const int*)d_in[0];
  const int*   lens  = (const int*)d_in[1];
  const int*   rels  = (const int*)d_in[2];
  const int*   nodes = (const int*)d_in[3];
  const float* adjw  = (const float*)d_in[4];
  const float* feat  = (const float*)d_in[5];
  const float* Wih   = (const float*)d_in[6];
  const float* Whh   = (const float*)d_in[7];
  const float* Wr    = (const float*)d_in[8];
  float* out = (float*)d_out;

  hipMemsetAsync(d_out, 0, (size_t)NS * OUTD * sizeof(float), stream);

  // ws layout: wt2 [0,360448) | fb bf16 feat [360448, 6760448) |
  //            ord [6760448, 6960448) | cnt/cur [6960448, +256)
  unsigned* wt2 = (unsigned*)d_ws;
  unsigned* fb  = (unsigned*)((char*)d_ws + 360448);
  int*      ord = (int*)((char*)d_ws + 6760448);
  int*      cnt = (int*)((char*)d_ws + 6960448);
  int*      cur = cnt + 32;

  wprep_kernel<<<NR, 256, 0, stream>>>(Wr, wt2);
  fprep_kernel<<<(NS * IND / 2 + 255) / 256, 256, 0, stream>>>(feat, fb);
  zero_cnt_kernel<<<1, 64, 0, stream>>>(cnt);
  hist_kernel<<<(NS + 255) / 256, 256, 0, stream>>>(lens, cnt);
  prefix_kernel<<<1, 64, 0, stream>>>(cnt, cur);
  scatter_kernel<<<(NS + 255) / 256, 256, 0, stream>>>(lens, cur, ord);

  lstm_mfma_kernel<<<(NS + 31) / 32, 512, 0, stream>>>(
      fb, nbr, lens, rels, adjw, Wih, Whh, ord, nodes, wt2, out, 0, NS);

  relu_kernel<<<(NS * OUTD / 4 + 255) / 256, 256, 0, stream>>>(
      (float4*)out, NS * OUTD / 4);
}